// Round 6
// baseline (984.795 us; speedup 1.0000x reference)
//
#include <hip/hip_runtime.h>
#include <math.h>

typedef __bf16 bf16;
typedef __bf16 bf16x8 __attribute__((ext_vector_type(8)));
typedef __bf16 bf16x4 __attribute__((ext_vector_type(4)));
typedef float  f32x4  __attribute__((ext_vector_type(4)));
typedef unsigned int u32;

#define MFMA16(a, b, c) __builtin_amdgcn_mfma_f32_16x16x32_bf16((a), (b), (c), 0, 0, 0)

__device__ __forceinline__ void async_copy16(const bf16* g, bf16* l) {
  __builtin_amdgcn_global_load_lds((const __attribute__((address_space(1))) void*)g,
                                   (__attribute__((address_space(3))) void*)l, 16, 0, 0);
}

// ---------- LN stats: per row (rstd, -mu*rstd) ----------
__global__ __launch_bounds__(256) void ln_stats_kernel(const float* __restrict__ x,
    float2* __restrict__ stats) {
  const int row = blockIdx.x * 4 + (threadIdx.x >> 6);
  const int lane = threadIdx.x & 63;
  const float* xr = x + (size_t)row * 768;
  float s = 0.f, ss = 0.f;
  for (int i = 0; i < 12; ++i) { float v = xr[lane + 64 * i]; s += v; ss += v * v; }
  for (int off = 32; off; off >>= 1) {
    s += __shfl_xor(s, off, 64); ss += __shfl_xor(ss, off, 64);
  }
  if (lane == 0) {
    float mu = s * (1.f / 768.f);
    float rstd = rsqrtf(ss * (1.f / 768.f) - mu * mu + 1e-5f);
    stats[row] = make_float2(rstd, -mu * rstd);
  }
}

// ---------- cast+transpose (+optional g-fold): Wt[n][k] = W[k][n] * g[k] ----------
__global__ __launch_bounds__(256) void castT_kernel(const float* __restrict__ in,
    const float* __restrict__ g, bf16* __restrict__ out, int K, int N) {
  __shared__ float tile[64][65];
  const int t = threadIdx.x;
  const int r = t >> 4, c4 = (t & 15) * 4;
  const int k0 = blockIdx.y * 64, n0 = blockIdx.x * 64;
  for (int it = 0; it < 4; ++it) {
    int row = r + it * 16;
    float gv = g ? g[k0 + row] : 1.f;
    const float4 v = *(const float4*)(in + (size_t)(k0 + row) * N + n0 + c4);
    tile[row][c4] = v.x * gv; tile[row][c4 + 1] = v.y * gv;
    tile[row][c4 + 2] = v.z * gv; tile[row][c4 + 3] = v.w * gv;
  }
  __syncthreads();
  for (int it = 0; it < 4; ++it) {
    int row = r + it * 16;
    bf16x4 v;
    for (int j = 0; j < 4; ++j) v[j] = (bf16)tile[c4 + j][row];
    *(bf16x4*)(out + (size_t)(n0 + row) * K + k0 + c4) = v;
  }
}

// ---------- colsum: bias[n] = (base? base[n]:0) + sum_k lnb[k] * W[k,n] ----------
__global__ __launch_bounds__(256) void colsum_kernel(const float* __restrict__ W,
    const float* __restrict__ lnb, const float* __restrict__ base,
    float* __restrict__ out, int K, int N) {
  const int col = blockIdx.x * 256 + threadIdx.x;
  float a = base ? base[col] : 0.f;
  for (int k = 0; k < K; ++k) a += lnb[k] * W[(size_t)k * N + col];
  out[col] = a;
}

// ---------- GEMM (m97): C[M,N] = A[M,K]@Bt[N,K]^T; ALN: A = (x-mu)*rstd on the fly ----
template <int ALN, int RES, int BIAS, int GELU, int OUTF32, int SPLIT>
__global__ __launch_bounds__(256) void gemm_bt(
    const bf16* __restrict__ A, const float* __restrict__ xf,
    const float2* __restrict__ stats,
    const bf16* __restrict__ Bt, int ldb,
    void* __restrict__ Cv, const float* __restrict__ bias, const float* __restrict__ res,
    bf16* __restrict__ qo, bf16* __restrict__ ko, bf16* __restrict__ vo,
    int M, int N, int K) {
  __shared__ bf16 As[4096];   // [128][32]
  __shared__ bf16 Bs[4096];   // [128][32]
  const int t = threadIdx.x;
  const int l = t & 63, w = t >> 6;
  const int lr = l >> 4, lc = l & 15;
  const int wm = w >> 1, wn = w & 1;
  const int m0 = blockIdx.y * 128, n0 = blockIdx.x * 128;

  const int srow = w * 16 + (l >> 2);
  const int scol = (l & 3) * 8;
  const bf16* gb0 = Bt + (size_t)(n0 + srow) * ldb + scol;
  const bf16* gb1 = Bt + (size_t)(n0 + 64 + srow) * ldb + scol;
  bf16* lb0 = &Bs[w * 512];
  bf16* lb1 = &Bs[2048 + w * 512];

  const bf16 *ga0, *ga1;
  bf16* la0 = &As[w * 512];
  bf16* la1 = &As[2048 + w * 512];
  const float* gx0;
  float2 st0, st1;
  const int arow = t >> 2, aoct = t & 3;
  if (ALN) {
    gx0 = xf + (size_t)(m0 + arow) * K + aoct * 8;
    st0 = stats[m0 + arow];
    st1 = stats[m0 + arow + 64];
  } else {
    ga0 = A + (size_t)(m0 + srow) * K + scol;
    ga1 = A + (size_t)(m0 + 64 + srow) * K + scol;
  }

  f32x4 acc[4][4];
  for (int i = 0; i < 4; ++i)
    for (int j = 0; j < 4; ++j) acc[i][j] = (f32x4){0.f, 0.f, 0.f, 0.f};

  for (int k0 = 0; k0 < K; k0 += 32) {
    async_copy16(gb0 + k0, lb0);
    async_copy16(gb1 + k0, lb1);
    if (ALN) {
      float4 u0 = *(const float4*)(gx0 + k0);
      float4 u1 = *(const float4*)(gx0 + k0 + 4);
      float4 u2 = *(const float4*)(gx0 + (size_t)64 * K + k0);
      float4 u3 = *(const float4*)(gx0 + (size_t)64 * K + k0 + 4);
      bf16x8 e0, e1;
      e0[0] = (bf16)(u0.x * st0.x + st0.y); e0[1] = (bf16)(u0.y * st0.x + st0.y);
      e0[2] = (bf16)(u0.z * st0.x + st0.y); e0[3] = (bf16)(u0.w * st0.x + st0.y);
      e0[4] = (bf16)(u1.x * st0.x + st0.y); e0[5] = (bf16)(u1.y * st0.x + st0.y);
      e0[6] = (bf16)(u1.z * st0.x + st0.y); e0[7] = (bf16)(u1.w * st0.x + st0.y);
      e1[0] = (bf16)(u2.x * st1.x + st1.y); e1[1] = (bf16)(u2.y * st1.x + st1.y);
      e1[2] = (bf16)(u2.z * st1.x + st1.y); e1[3] = (bf16)(u2.w * st1.x + st1.y);
      e1[4] = (bf16)(u3.x * st1.x + st1.y); e1[5] = (bf16)(u3.y * st1.x + st1.y);
      e1[6] = (bf16)(u3.z * st1.x + st1.y); e1[7] = (bf16)(u3.w * st1.x + st1.y);
      *(bf16x8*)&As[arow * 32 + aoct * 8] = e0;
      *(bf16x8*)&As[(arow + 64) * 32 + aoct * 8] = e1;
    } else {
      async_copy16(ga0 + k0, la0);
      async_copy16(ga1 + k0, la1);
    }
    __syncthreads();
    bf16x8 af[4], bfr[4];
    for (int i = 0; i < 4; ++i)
      af[i] = *(const bf16x8*)&As[(wm * 64 + i * 16 + lc) * 32 + 8 * lr];
    for (int j = 0; j < 4; ++j)
      bfr[j] = *(const bf16x8*)&Bs[(wn * 64 + j * 16 + lc) * 32 + 8 * lr];
    for (int i = 0; i < 4; ++i)
      for (int j = 0; j < 4; ++j)
        acc[i][j] = MFMA16(af[i], bfr[j], acc[i][j]);
    __syncthreads();
  }

  const size_t Ns = (size_t)N;
  for (int i = 0; i < 4; ++i) {
    int rowb = m0 + wm * 64 + i * 16 + lr * 4;
    for (int j = 0; j < 4; ++j) {
      int col = n0 + wn * 64 + j * 16 + lc;
      float bv = BIAS ? bias[col] : 0.f;
      for (int r = 0; r < 4; ++r) {
        int row = rowb + r;
        float vv = acc[i][j][r];
        if (BIAS) vv += bv;
        if (GELU) vv = 0.5f * vv * (1.f + erff(vv * 0.70710678118654752f));
        if (RES)  vv += res[(size_t)row * Ns + col];
        if (SPLIT) {
          int which = col / 768;
          int rem = col - which * 768;
          int d = rem / 12, h = rem - d * 12;
          int bb = row >> 11, tt = row & 2047;
          bf16* dst = which == 0 ? qo : (which == 1 ? ko : vo);
          dst[((size_t)((bb * 12 + h) * 2048 + tt)) * 64 + d] = (bf16)vv;
        } else if (OUTF32) {
          ((float*)Cv)[(size_t)row * Ns + col] = vv;
        } else {
          ((bf16*)Cv)[(size_t)row * Ns + col] = (bf16)vv;
        }
      }
    }
  }
}

// ---------- Flash attention v2: KB=64, prefetch, packed V stores ----------
__global__ __launch_bounds__(256) void attn_kernel(const bf16* __restrict__ q,
    const bf16* __restrict__ k, const bf16* __restrict__ v, bf16* __restrict__ out) {
  __shared__ bf16 Ks[64 * 72];     // [key][72 pad]
  __shared__ bf16 Vt[64 * 72];     // [d][72], key col rotated by 8*(d>>3) mod 64
  __shared__ bf16 Ps[4 * 16 * 72]; // per-wave P: [16 rows][72]
  const int t = threadIdx.x;
  const int l = t & 63, w = t >> 6;
  const int g = l >> 4, c = l & 15;
  const int bh = blockIdx.y;
  const int q0 = blockIdx.x * 64;
  const size_t base = (size_t)bh * (2048 * 64);
  bf16x8 aq0 = *(const bf16x8*)(q + base + (size_t)(q0 + w * 16 + c) * 64 + 8 * g);
  bf16x8 aq1 = *(const bf16x8*)(q + base + (size_t)(q0 + w * 16 + c) * 64 + 32 + 8 * g);
  f32x4 O[4];
  for (int j = 0; j < 4; ++j) O[j] = (f32x4){0.f, 0.f, 0.f, 0.f};
  float m_i[4], l_i[4];
  for (int r = 0; r < 4; ++r) { m_i[r] = -1e30f; l_i[r] = 0.f; }
  const int rr = t >> 3, so = t & 7;       // keys 2rr, 2rr+1 ; d-octet so
  const float cs = 0.125f * 1.44269504089f;

  const bf16* kp = k + base + (size_t)(2 * rr) * 64 + so * 8;
  const bf16* vp = v + base + (size_t)(2 * rr) * 64 + so * 8;
  bf16x8 kr0 = *(const bf16x8*)kp;
  bf16x8 kr1 = *(const bf16x8*)(kp + 64);
  bf16x8 vr0 = *(const bf16x8*)vp;
  bf16x8 vr1 = *(const bf16x8*)(vp + 64);

  for (int j0 = 0; j0 < 2048; j0 += 64) {
    __syncthreads();   // previous chunk's LDS readers done
    *(bf16x8*)&Ks[(2 * rr) * 72 + so * 8] = kr0;
    *(bf16x8*)&Ks[(2 * rr + 1) * 72 + so * 8] = kr1;
    {
      int keyr = (2 * rr + 8 * so) & 63;   // rotation: dd>>3 == so
      for (int i = 0; i < 8; ++i) {
        int dd = so * 8 + i;
        union { bf16 h[2]; u32 u; } pu;
        pu.h[0] = vr0[i]; pu.h[1] = vr1[i];
        *(u32*)&Vt[dd * 72 + keyr] = pu.u;
      }
    }
    if (j0 + 64 < 2048) {      // prefetch next chunk (overlaps with compute below)
      kp += 64 * 64; vp += 64 * 64;
      kr0 = *(const bf16x8*)kp;
      kr1 = *(const bf16x8*)(kp + 64);
      vr0 = *(const bf16x8*)vp;
      vr1 = *(const bf16x8*)(vp + 64);
    }
    __syncthreads();   // Ks/Vt visible
    // S = Q K^T : 4 key-tiles
    f32x4 S[4];
    for (int m = 0; m < 4; ++m) {
      S[m] = (f32x4){0.f, 0.f, 0.f, 0.f};
      bf16x8 b0 = *(const bf16x8*)&Ks[(16 * m + c) * 72 + 8 * g];
      bf16x8 b1 = *(const bf16x8*)&Ks[(16 * m + c) * 72 + 32 + 8 * g];
      S[m] = MFMA16(aq0, b0, S[m]);
      S[m] = MFMA16(aq1, b1, S[m]);
    }
    float mx[4];
    for (int r = 0; r < 4; ++r) {
      for (int m = 0; m < 4; ++m) S[m][r] *= cs;
      mx[r] = fmaxf(fmaxf(S[0][r], S[1][r]), fmaxf(S[2][r], S[3][r]));
    }
    for (int off = 1; off < 16; off <<= 1)
      for (int r = 0; r < 4; ++r) mx[r] = fmaxf(mx[r], __shfl_xor(mx[r], off, 64));
    float alpha[4], rs_[4];
    for (int r = 0; r < 4; ++r) {
      float mn = fmaxf(m_i[r], mx[r]);
      alpha[r] = exp2f(m_i[r] - mn);
      m_i[r] = mn;
      rs_[r] = 0.f;
    }
    for (int r = 0; r < 4; ++r) {
      for (int m = 0; m < 4; ++m) {
        float p = exp2f(S[m][r] - m_i[r]);
        bf16 pb = (bf16)p;
        Ps[w * 1152 + (g * 4 + r) * 72 + 16 * m + c] = pb;
        rs_[r] += (float)pb;
      }
    }
    for (int off = 1; off < 16; off <<= 1)
      for (int r = 0; r < 4; ++r) rs_[r] += __shfl_xor(rs_[r], off, 64);
    for (int r = 0; r < 4; ++r) l_i[r] = l_i[r] * alpha[r] + rs_[r];
    for (int j = 0; j < 4; ++j)
      for (int r = 0; r < 4; ++r) O[j][r] *= alpha[r];
    // P is wave-private; DS ops in-order per wave -> no barrier needed
    bf16x8 ap0 = *(const bf16x8*)&Ps[w * 1152 + c * 72 + 8 * g];
    bf16x8 ap1 = *(const bf16x8*)&Ps[w * 1152 + c * 72 + 32 + 8 * g];
    for (int j = 0; j < 4; ++j) {
      int dd = j * 16 + c;
      int rot = 8 * (dd >> 3);
      bf16x8 bv0 = *(const bf16x8*)&Vt[dd * 72 + ((8 * g + rot) & 63)];
      bf16x8 bv1 = *(const bf16x8*)&Vt[dd * 72 + ((32 + 8 * g + rot) & 63)];
      O[j] = MFMA16(ap0, bv0, O[j]);
      O[j] = MFMA16(ap1, bv1, O[j]);
    }
  }
  const int b = bh / 12, h = bh % 12;
  for (int j = 0; j < 4; ++j)
    for (int r = 0; r < 4; ++r) {
      int tok = q0 + w * 16 + g * 4 + r;
      int col = h * 64 + j * 16 + c;
      out[(size_t)(b * 2048 + tok) * 768 + col] = (bf16)(O[j][r] / l_i[r]);
    }
}

// ---------- launch ----------
extern "C" void kernel_launch(void* const* d_in, const int* in_sizes, int n_in,
                              void* d_out, int out_size, void* d_ws, size_t ws_size,
                              hipStream_t stream) {
  static const long expected[9] = {6291456, 768, 768, 1769472, 589824, 2359296,
                                   3072, 2359296, 768};
  long f = 1; bool found = false;
  for (long ff = 1; ff <= 4 && !found; ff *= 2)
    for (int i = 0; i < n_in; ++i)
      if ((long)in_sizes[i] == 6291456L * ff) { f = ff; found = true; break; }
  int idx[9]; bool used[32] = {false};
  for (int s = 0; s < 9; ++s) {
    idx[s] = -1;
    if (found)
      for (int i = 0; i < n_in; ++i)
        if (!used[i] && (long)in_sizes[i] == expected[s] * f) { idx[s] = i; used[i] = true; break; }
    if (idx[s] < 0) idx[s] = s;
  }
  const float* x    = (const float*)d_in[idx[0]];
  const float* ln_g = (const float*)d_in[idx[1]];
  const float* ln_b = (const float*)d_in[idx[2]];
  const float* wqkv = (const float*)d_in[idx[3]];
  const float* wao  = (const float*)d_in[idx[4]];
  const float* wi   = (const float*)d_in[idx[5]];
  const float* bi   = (const float*)d_in[idx[6]];
  const float* wo   = (const float*)d_in[idx[7]];
  const float* bo   = (const float*)d_in[idx[8]];

  char* ws = (char*)d_ws;
  // ws map (bytes), peak < 37,748,736 (proven available):
  bf16*   wtq    = (bf16*)(ws + 0);            // 3,538,944 (t0 .. qkv)
  bf16*   wti    = (bf16*)(ws + 0);            // 4,718,592 (post-qkv .. h1)
  bf16*   wto    = (bf16*)(ws + 4718592);      // 4,718,592 (post-qkv .. out1)
  bf16*   at     = (bf16*)(ws + 9437184);      // 12,582,912 (attn .. proj)
  bf16*   hbuf   = (bf16*)(ws + 9437184);      // 25,165,824 (post-proj; overlays at)
  bf16*   qb     = (bf16*)(ws + 22544384);     // 12,582,912 (qkv .. attn)
  float*  bias_q = (float*)(ws + 35127296);    // 9,216
  float*  bias_h = (float*)(ws + 35136512);    // 12,288
  bf16*   wta    = (bf16*)(ws + 35160064);     // 1,179,648 (.. proj)
  float2* stats  = (float2*)(ws + 37617664);   // 65,536
  bf16*   kb     = (bf16*)d_out;
  bf16*   vb     = (bf16*)((char*)d_out + 12582912);
  float*  x1     = (float*)d_out;

  ln_stats_kernel<<<2048, 256, 0, stream>>>(x, stats);
  castT_kernel<<<dim3(36, 12), 256, 0, stream>>>(wqkv, ln_g, wtq, 768, 2304);
  colsum_kernel<<<9, 256, 0, stream>>>(wqkv, ln_b, nullptr, bias_q, 768, 2304);
  // qkv = LN(x) @ w_qkv  (A on the fly; split-scatter)
  gemm_bt<1,0,1,0,0,1><<<dim3(18, 64), 256, 0, stream>>>(
      nullptr, x, stats, wtq, 768, nullptr, bias_q, nullptr, qb, kb, vb, 8192, 2304, 768);
  castT_kernel<<<dim3(12, 12), 256, 0, stream>>>(wao, nullptr, wta, 768, 768);
  castT_kernel<<<dim3(48, 12), 256, 0, stream>>>(wi, ln_g, wti, 768, 3072);
  castT_kernel<<<dim3(12, 48), 256, 0, stream>>>(wo, nullptr, wto, 3072, 768);
  colsum_kernel<<<12, 256, 0, stream>>>(wi, ln_b, bi, bias_h, 768, 3072);
  attn_kernel<<<dim3(32, 48), 256, 0, stream>>>(qb, kb, vb, at);
  // x1 = x + at @ w_attn_out  (fp32 into d_out; k/v dead)
  gemm_bt<0,1,0,0,1,0><<<dim3(6, 64), 256, 0, stream>>>(
      at, nullptr, nullptr, wta, 768, x1, nullptr, x, nullptr, nullptr, nullptr,
      8192, 768, 768);
  // MLP: two 1536-wide slices; x1 accumulates in place
  for (int s = 0; s < 2; ++s) {
    gemm_bt<1,0,1,1,0,0><<<dim3(12, 64), 256, 0, stream>>>(
        nullptr, x, stats, wti + (size_t)s * 1536 * 768, 768, hbuf,
        bias_h + s * 1536, nullptr, nullptr, nullptr, nullptr, 8192, 1536, 768);
    if (s == 0)
      gemm_bt<0,1,0,0,1,0><<<dim3(6, 64), 256, 0, stream>>>(
          hbuf, nullptr, nullptr, wto, 3072, x1, nullptr, x1, nullptr, nullptr, nullptr,
          8192, 768, 1536);
    else
      gemm_bt<0,1,1,0,1,0><<<dim3(6, 64), 256, 0, stream>>>(
          hbuf, nullptr, nullptr, wto + 1536, 3072, x1, bo, x1, nullptr, nullptr, nullptr,
          8192, 768, 1536);
  }
}

// Round 7
// 575.383 us; speedup vs baseline: 1.7115x; 1.7115x over previous
//
#include <hip/hip_runtime.h>
#include <math.h>

typedef __bf16 bf16;
typedef __bf16 bf16x8 __attribute__((ext_vector_type(8)));
typedef __bf16 bf16x4 __attribute__((ext_vector_type(4)));
typedef float  f32x4  __attribute__((ext_vector_type(4)));
typedef unsigned int u32;

#define MFMA16(a, b, c) __builtin_amdgcn_mfma_f32_16x16x32_bf16((a), (b), (c), 0, 0, 0)

__device__ __forceinline__ void async_copy16(const bf16* g, bf16* l) {
  __builtin_amdgcn_global_load_lds((const __attribute__((address_space(1))) void*)g,
                                   (__attribute__((address_space(3))) void*)l, 16, 0, 0);
}

// ---------- LayerNorm: fp32 x -> bf16 norm. One block/token ----------
__global__ __launch_bounds__(256) void ln_kernel(const float* __restrict__ x,
    const float* __restrict__ g, const float* __restrict__ b, bf16* __restrict__ nrm) {
  const int tok = blockIdx.x, t = threadIdx.x;
  const float* xr = x + (size_t)tok * 768;
  float v0 = xr[t], v1 = xr[t + 256], v2 = xr[t + 512];
  float s = v0 + v1 + v2, ss = v0 * v0 + v1 * v1 + v2 * v2;
  for (int off = 32; off; off >>= 1) {
    s += __shfl_down(s, off, 64); ss += __shfl_down(ss, off, 64);
  }
  __shared__ float red[8];
  if ((t & 63) == 0) { red[(t >> 6) * 2] = s; red[(t >> 6) * 2 + 1] = ss; }
  __syncthreads();
  s = red[0] + red[2] + red[4] + red[6];
  ss = red[1] + red[3] + red[5] + red[7];
  float mu = s * (1.f / 768.f);
  float rstd = rsqrtf(ss * (1.f / 768.f) - mu * mu + 1e-5f);
  bf16* o = nrm + (size_t)tok * 768;
  o[t]       = (bf16)((v0 - mu) * rstd * g[t]       + b[t]);
  o[t + 256] = (bf16)((v1 - mu) * rstd * g[t + 256] + b[t + 256]);
  o[t + 512] = (bf16)((v2 - mu) * rstd * g[t + 512] + b[t + 512]);
}

// ---------- cast+transpose: Wt[n][k] = (bf16)W[k][n] ----------
__global__ __launch_bounds__(256) void castT_kernel(const float* __restrict__ in,
    bf16* __restrict__ out, int K, int N) {
  __shared__ float tile[64][65];
  const int t = threadIdx.x;
  const int r = t >> 4, c4 = (t & 15) * 4;
  const int k0 = blockIdx.y * 64, n0 = blockIdx.x * 64;
  for (int it = 0; it < 4; ++it) {
    int row = r + it * 16;
    const float4 v = *(const float4*)(in + (size_t)(k0 + row) * N + n0 + c4);
    tile[row][c4] = v.x; tile[row][c4 + 1] = v.y;
    tile[row][c4 + 2] = v.z; tile[row][c4 + 3] = v.w;
  }
  __syncthreads();
  for (int it = 0; it < 4; ++it) {
    int row = r + it * 16;
    bf16x4 v;
    for (int j = 0; j < 4; ++j) v[j] = (bf16)tile[c4 + j][row];
    *(bf16x4*)(out + (size_t)(n0 + row) * K + k0 + c4) = v;
  }
}

// ---------- GEMM: C[M,N] = A[M,K]@Bt[N,K]^T; MT=128 (m97) or 64 (high-occupancy) ----
template <int MT, int RES, int BIAS, int GELU, int OUTF32, int SPLIT>
__global__ __launch_bounds__(256) void gemm_bt(
    const bf16* __restrict__ A, const bf16* __restrict__ Bt, int ldb,
    void* __restrict__ Cv, const float* __restrict__ bias, const float* __restrict__ res,
    bf16* __restrict__ qo, bf16* __restrict__ ko, bf16* __restrict__ vo,
    int M, int N, int K) {
  constexpr int NJ = (MT == 128) ? 4 : 2;   // n-tiles per wave
  __shared__ bf16 As[MT * 32];
  __shared__ bf16 Bs[128 * 32];
  const int t = threadIdx.x;
  const int l = t & 63, w = t >> 6;
  const int lr = l >> 4, lc = l & 15;
  const int wm = (MT == 128) ? (w >> 1) : 0;
  const int wn = (MT == 128) ? (w & 1) : w;
  const int m0 = blockIdx.y * MT, n0 = blockIdx.x * 128;

  const int srow = t >> 2;          // 0..63
  const int scol = (t & 3) * 8;
  const bf16* ga0 = A + (size_t)(m0 + srow) * K + scol;
  const bf16* ga1 = A + (size_t)(m0 + 64 + srow) * K + scol;   // MT==128 only
  const bf16* gb0 = Bt + (size_t)(n0 + srow) * ldb + scol;
  const bf16* gb1 = Bt + (size_t)(n0 + 64 + srow) * ldb + scol;
  bf16* la0 = &As[w * 512];
  bf16* lb0 = &Bs[w * 512];
  bf16* lb1 = &Bs[2048 + w * 512];

  f32x4 acc[4][NJ];
  for (int i = 0; i < 4; ++i)
    for (int j = 0; j < NJ; ++j) acc[i][j] = (f32x4){0.f, 0.f, 0.f, 0.f};

  for (int k0 = 0; k0 < K; k0 += 32) {
    async_copy16(ga0 + k0, la0);
    if (MT == 128) async_copy16(ga1 + k0, &As[2048 + w * 512]);
    async_copy16(gb0 + k0, lb0);
    async_copy16(gb1 + k0, lb1);
    __syncthreads();
    bf16x8 af[4], bfr[NJ];
    for (int i = 0; i < 4; ++i)
      af[i] = *(const bf16x8*)&As[(wm * 64 + i * 16 + lc) * 32 + 8 * lr];
    for (int j = 0; j < NJ; ++j)
      bfr[j] = *(const bf16x8*)&Bs[(wn * 16 * NJ + j * 16 + lc) * 32 + 8 * lr];
    for (int i = 0; i < 4; ++i)
      for (int j = 0; j < NJ; ++j)
        acc[i][j] = MFMA16(af[i], bfr[j], acc[i][j]);
    __syncthreads();
  }

  const size_t Ns = (size_t)N;
  for (int i = 0; i < 4; ++i) {
    int rowb = m0 + wm * 64 + i * 16 + lr * 4;
    for (int j = 0; j < NJ; ++j) {
      int col = n0 + wn * 16 * NJ + j * 16 + lc;
      float bv = BIAS ? bias[col] : 0.f;
      for (int r = 0; r < 4; ++r) {
        int row = rowb + r;
        float vv = acc[i][j][r];
        if (BIAS) vv += bv;
        if (GELU) vv = 0.5f * vv * (1.f + erff(vv * 0.70710678118654752f));
        if (RES)  vv += res[(size_t)row * Ns + col];
        if (SPLIT) {
          int which = col / 768;
          int rem = col - which * 768;
          int d = rem / 12, h = rem - d * 12;
          int bb = row >> 11, tt = row & 2047;
          bf16* dst = which == 0 ? qo : (which == 1 ? ko : vo);
          dst[((size_t)((bb * 12 + h) * 2048 + tt)) * 64 + d] = (bf16)vv;
        } else if (OUTF32) {
          ((float*)Cv)[(size_t)row * Ns + col] = vv;
        } else {
          ((bf16*)Cv)[(size_t)row * Ns + col] = (bf16)vv;
        }
      }
    }
  }
}

// ---------- Flash attention v3: no online max (bounded S), ones-frag rowsum ----------
// block = (bh, 128 q rows); 4 waves x 32 rows; KB=64, K/V reg prefetch.
__global__ __launch_bounds__(256) void attn_kernel(const bf16* __restrict__ q,
    const bf16* __restrict__ k, const bf16* __restrict__ v, bf16* __restrict__ out) {
  __shared__ bf16 Ks[64 * 72];      // [key][72 pad]
  __shared__ bf16 Vt[64 * 72];      // [d][72], key col rotated by 8*(d>>3) mod 64
  __shared__ bf16 Ps[4 * 32 * 72];  // per-wave P: [32 rows][72]
  const int t = threadIdx.x;
  const int l = t & 63, w = t >> 6;
  const int g = l >> 4, c = l & 15;
  const int bh = blockIdx.y;
  const int q0 = blockIdx.x * 128;
  const size_t base = (size_t)bh * (2048 * 64);
  const int qr = q0 + w * 32;
  bf16x8 aq[2][2];
  for (int rt = 0; rt < 2; ++rt) {
    aq[rt][0] = *(const bf16x8*)(q + base + (size_t)(qr + rt * 16 + c) * 64 + 8 * g);
    aq[rt][1] = *(const bf16x8*)(q + base + (size_t)(qr + rt * 16 + c) * 64 + 32 + 8 * g);
  }
  f32x4 O[2][4], O5[2];
  for (int rt = 0; rt < 2; ++rt) {
    for (int j = 0; j < 4; ++j) O[rt][j] = (f32x4){0.f, 0.f, 0.f, 0.f};
    O5[rt] = (f32x4){0.f, 0.f, 0.f, 0.f};
  }
  bf16x8 ones;
  for (int i = 0; i < 8; ++i) ones[i] = (bf16)1.0f;
  const int rr = t >> 3, so = t & 7;        // staging: keys 2rr,2rr+1 ; d-octet so
  const float cs = 0.125f * 1.44269504089f; // scale * log2(e)

  const bf16* kp = k + base + (size_t)(2 * rr) * 64 + so * 8;
  const bf16* vp = v + base + (size_t)(2 * rr) * 64 + so * 8;
  bf16x8 kr0 = *(const bf16x8*)kp;
  bf16x8 kr1 = *(const bf16x8*)(kp + 64);
  bf16x8 vr0 = *(const bf16x8*)vp;
  bf16x8 vr1 = *(const bf16x8*)(vp + 64);

  for (int j0 = 0; j0 < 2048; j0 += 64) {
    __syncthreads();   // previous chunk's LDS readers done
    *(bf16x8*)&Ks[(2 * rr) * 72 + so * 8] = kr0;
    *(bf16x8*)&Ks[(2 * rr + 1) * 72 + so * 8] = kr1;
    {
      int keyr = (2 * rr + 8 * so) & 63;
      for (int i = 0; i < 8; ++i) {
        int dd = so * 8 + i;
        union { bf16 h[2]; u32 u; } pu;
        pu.h[0] = vr0[i]; pu.h[1] = vr1[i];
        *(u32*)&Vt[dd * 72 + keyr] = pu.u;
      }
    }
    if (j0 + 64 < 2048) {
      kp += 64 * 64; vp += 64 * 64;
      kr0 = *(const bf16x8*)kp;
      kr1 = *(const bf16x8*)(kp + 64);
      vr0 = *(const bf16x8*)vp;
      vr1 = *(const bf16x8*)(vp + 64);
    }
    __syncthreads();   // Ks/Vt visible
    // S = Q K^T : 4 key-tiles x 2 row-tiles (Ks fragments shared across row-tiles)
    f32x4 S[2][4];
    for (int m = 0; m < 4; ++m) {
      bf16x8 b0 = *(const bf16x8*)&Ks[(16 * m + c) * 72 + 8 * g];
      bf16x8 b1 = *(const bf16x8*)&Ks[(16 * m + c) * 72 + 32 + 8 * g];
      for (int rt = 0; rt < 2; ++rt) {
        f32x4 z = (f32x4){0.f, 0.f, 0.f, 0.f};
        z = MFMA16(aq[rt][0], b0, z);
        S[rt][m] = MFMA16(aq[rt][1], b1, z);
      }
    }
    // P = exp2(S*cs) directly (no max subtraction; |S*cs| << 127 with LN'd inputs)
    for (int rt = 0; rt < 2; ++rt)
      for (int m = 0; m < 4; ++m)
        for (int r = 0; r < 4; ++r) {
          float p = exp2f(S[rt][m][r] * cs);
          Ps[w * 2304 + (rt * 16 + g * 4 + r) * 72 + 16 * m + c] = (bf16)p;
        }
    // P round-trip (wave-private, in-order DS: no barrier)
    bf16x8 ap[2][2];
    for (int rt = 0; rt < 2; ++rt) {
      ap[rt][0] = *(const bf16x8*)&Ps[w * 2304 + (rt * 16 + c) * 72 + 8 * g];
      ap[rt][1] = *(const bf16x8*)&Ps[w * 2304 + (rt * 16 + c) * 72 + 32 + 8 * g];
    }
    for (int j = 0; j < 4; ++j) {
      int dd = j * 16 + c;
      int rot = 8 * (dd >> 3);
      bf16x8 bv0 = *(const bf16x8*)&Vt[dd * 72 + ((8 * g + rot) & 63)];
      bf16x8 bv1 = *(const bf16x8*)&Vt[dd * 72 + ((32 + 8 * g + rot) & 63)];
      for (int rt = 0; rt < 2; ++rt) {
        O[rt][j] = MFMA16(ap[rt][0], bv0, O[rt][j]);
        O[rt][j] = MFMA16(ap[rt][1], bv1, O[rt][j]);
      }
    }
    for (int rt = 0; rt < 2; ++rt) {       // rowsum via constant ones B-frag
      O5[rt] = MFMA16(ap[rt][0], ones, O5[rt]);
      O5[rt] = MFMA16(ap[rt][1], ones, O5[rt]);
    }
  }
  const int b = bh / 12, h = bh % 12;
  for (int rt = 0; rt < 2; ++rt)
    for (int r = 0; r < 4; ++r) {
      float inv = 1.0f / O5[rt][r];
      int tok = q0 + w * 32 + rt * 16 + g * 4 + r;
      for (int j = 0; j < 4; ++j) {
        int col = h * 64 + j * 16 + c;
        out[(size_t)(b * 2048 + tok) * 768 + col] = (bf16)(O[rt][j][r] * inv);
      }
    }
}

// ---------- launch ----------
extern "C" void kernel_launch(void* const* d_in, const int* in_sizes, int n_in,
                              void* d_out, int out_size, void* d_ws, size_t ws_size,
                              hipStream_t stream) {
  static const long expected[9] = {6291456, 768, 768, 1769472, 589824, 2359296,
                                   3072, 2359296, 768};
  long f = 1; bool found = false;
  for (long ff = 1; ff <= 4 && !found; ff *= 2)
    for (int i = 0; i < n_in; ++i)
      if ((long)in_sizes[i] == 6291456L * ff) { f = ff; found = true; break; }
  int idx[9]; bool used[32] = {false};
  for (int s = 0; s < 9; ++s) {
    idx[s] = -1;
    if (found)
      for (int i = 0; i < n_in; ++i)
        if (!used[i] && (long)in_sizes[i] == expected[s] * f) { idx[s] = i; used[i] = true; break; }
    if (idx[s] < 0) idx[s] = s;
  }
  const float* x    = (const float*)d_in[idx[0]];
  const float* ln_g = (const float*)d_in[idx[1]];
  const float* ln_b = (const float*)d_in[idx[2]];
  const float* wqkv = (const float*)d_in[idx[3]];
  const float* wao  = (const float*)d_in[idx[4]];
  const float* wi   = (const float*)d_in[idx[5]];
  const float* bi   = (const float*)d_in[idx[6]];
  const float* wo   = (const float*)d_in[idx[7]];
  const float* bo   = (const float*)d_in[idx[8]];

  char* ws = (char*)d_ws;
  // ws timeline: norm[0,12.58M) lives ln->last h-GEMM.
  //   wtq[12.58,16.12M) cast->qkv; then at[12.58,25.17M) attn->proj; then hbuf same spot.
  //   qb[25.17,37.75M) qkv->attn; then wta/wti/wto [25.17,35.78M) post-attn.
  // d_out: kb[0,12.58M) vb[12.58,25.17M) qkv->attn; then x1 fp32 [0,24M) = final out.
  bf16*  norm = (bf16*)(ws);
  bf16*  wtq  = (bf16*)(ws + 12582912);
  bf16*  at   = (bf16*)(ws + 12582912);
  bf16*  hbuf = (bf16*)(ws + 12582912);
  bf16*  qb   = (bf16*)(ws + 25165824);
  bf16*  wta  = (bf16*)(ws + 25165824);
  bf16*  wti  = (bf16*)(ws + 26345472);
  bf16*  wto  = (bf16*)(ws + 31064064);
  bf16*  kb   = (bf16*)d_out;
  bf16*  vb   = (bf16*)((char*)d_out + 12582912);
  float* x1   = (float*)d_out;

  ln_kernel<<<8192, 256, 0, stream>>>(x, ln_g, ln_b, norm);
  castT_kernel<<<dim3(36, 12), 256, 0, stream>>>(wqkv, wtq, 768, 2304);
  gemm_bt<128,0,0,0,0,1><<<dim3(18, 64), 256, 0, stream>>>(
      norm, wtq, 768, nullptr, nullptr, nullptr, qb, kb, vb, 8192, 2304, 768);
  attn_kernel<<<dim3(16, 48), 256, 0, stream>>>(qb, kb, vb, at);
  castT_kernel<<<dim3(12, 12), 256, 0, stream>>>(wao, wta, 768, 768);
  castT_kernel<<<dim3(48, 12), 256, 0, stream>>>(wi,  wti, 768, 3072);
  castT_kernel<<<dim3(12, 48), 256, 0, stream>>>(wo,  wto, 3072, 768);
  // x1 = x + at @ w_attn_out  (fp32 into d_out; k/v dead)
  gemm_bt<64,1,0,0,1,0><<<dim3(6, 128), 256, 0, stream>>>(
      at, wta, 768, x1, nullptr, x, nullptr, nullptr, nullptr, 8192, 768, 768);
  // MLP: 4 x 768-wide slices; x1 accumulates in place
  for (int p = 0; p < 4; ++p) {
    gemm_bt<64,0,1,1,0,0><<<dim3(6, 128), 256, 0, stream>>>(
        norm, wti + (size_t)p * 768 * 768, 768, hbuf, bi + p * 768, nullptr,
        nullptr, nullptr, nullptr, 8192, 768, 768);
    if (p < 3)
      gemm_bt<64,1,0,0,1,0><<<dim3(6, 128), 256, 0, stream>>>(
          hbuf, wto + (size_t)p * 768, 3072, x1, nullptr, x1,
          nullptr, nullptr, nullptr, 8192, 768, 768);
    else
      gemm_bt<64,1,1,0,1,0><<<dim3(6, 128), 256, 0, stream>>>(
          hbuf, wto + (size_t)p * 768, 3072, x1, bo, x1,
          nullptr, nullptr, nullptr, 8192, 768, 768);
  }
}

// Round 8
// 462.886 us; speedup vs baseline: 2.1275x; 1.2430x over previous
//
#include <hip/hip_runtime.h>
#include <math.h>

typedef __bf16 bf16;
typedef __bf16 bf16x8 __attribute__((ext_vector_type(8)));
typedef __bf16 bf16x4 __attribute__((ext_vector_type(4)));
typedef float  f32x4  __attribute__((ext_vector_type(4)));
typedef unsigned int u32;

#define MFMA16(a, b, c) __builtin_amdgcn_mfma_f32_16x16x32_bf16((a), (b), (c), 0, 0, 0)

__device__ __forceinline__ void async_copy16(const bf16* g, bf16* l) {
  __builtin_amdgcn_global_load_lds((const __attribute__((address_space(1))) void*)g,
                                   (__attribute__((address_space(3))) void*)l, 16, 0, 0);
}

// ---------- LayerNorm: fp32 x -> bf16 norm. One block/token ----------
__global__ __launch_bounds__(256) void ln_kernel(const float* __restrict__ x,
    const float* __restrict__ g, const float* __restrict__ b, bf16* __restrict__ nrm) {
  const int tok = blockIdx.x, t = threadIdx.x;
  const float* xr = x + (size_t)tok * 768;
  float v0 = xr[t], v1 = xr[t + 256], v2 = xr[t + 512];
  float s = v0 + v1 + v2, ss = v0 * v0 + v1 * v1 + v2 * v2;
  for (int off = 32; off; off >>= 1) {
    s += __shfl_down(s, off, 64); ss += __shfl_down(ss, off, 64);
  }
  __shared__ float red[8];
  if ((t & 63) == 0) { red[(t >> 6) * 2] = s; red[(t >> 6) * 2 + 1] = ss; }
  __syncthreads();
  s = red[0] + red[2] + red[4] + red[6];
  ss = red[1] + red[3] + red[5] + red[7];
  float mu = s * (1.f / 768.f);
  float rstd = rsqrtf(ss * (1.f / 768.f) - mu * mu + 1e-5f);
  bf16* o = nrm + (size_t)tok * 768;
  o[t]       = (bf16)((v0 - mu) * rstd * g[t]       + b[t]);
  o[t + 256] = (bf16)((v1 - mu) * rstd * g[t + 256] + b[t + 256]);
  o[t + 512] = (bf16)((v2 - mu) * rstd * g[t + 512] + b[t + 512]);
}

// ---------- cast+transpose: Wt[n'][k] = (bf16)W[k][n]; PERM remaps qkv cols ----------
// PERM: n = which*768 + d*12 + h  ->  n' = which*768 + h*64 + d  (attn-friendly order)
template <int PERM>
__global__ __launch_bounds__(256) void castT_kernel(const float* __restrict__ in,
    bf16* __restrict__ out, int K, int N) {
  __shared__ float tile[64][65];
  const int t = threadIdx.x;
  const int r = t >> 4, c4 = (t & 15) * 4;
  const int k0 = blockIdx.y * 64, n0 = blockIdx.x * 64;
  for (int it = 0; it < 4; ++it) {
    int row = r + it * 16;
    const float4 v = *(const float4*)(in + (size_t)(k0 + row) * N + n0 + c4);
    tile[row][c4] = v.x; tile[row][c4 + 1] = v.y;
    tile[row][c4 + 2] = v.z; tile[row][c4 + 3] = v.w;
  }
  __syncthreads();
  for (int it = 0; it < 4; ++it) {
    int row = r + it * 16;
    int n = n0 + row;
    if (PERM) {
      int which = n / 768, rem = n - which * 768;
      int d = rem / 12, h = rem - d * 12;
      n = which * 768 + h * 64 + d;
    }
    bf16x4 v;
    for (int j = 0; j < 4; ++j) v[j] = (bf16)tile[c4 + j][row];
    *(bf16x4*)(out + (size_t)n * K + k0 + c4) = v;
  }
}

// ---------- GEMM: C[M,N] = A[M,K]@Bt[N,K]^T; BK=64 (two 32-wide LDS halves) ----------
// MT=128 (2x2 waves, NJ=4) or MT=64 (1x4 waves, NJ=2). K % 64 == 0.
template <int MT, int RES, int BIAS, int GELU, int OUTF32, int SPLIT>
__global__ __launch_bounds__(256) void gemm_bt(
    const bf16* __restrict__ A, const bf16* __restrict__ Bt, int ldb,
    void* __restrict__ Cv, const float* __restrict__ bias, const float* __restrict__ res,
    bf16* __restrict__ qo, bf16* __restrict__ ko, bf16* __restrict__ vo,
    int M, int N, int K) {
  constexpr int NJ = (MT == 128) ? 4 : 2;
  constexpr int AH = MT * 32;              // elements per k-half of A
  __shared__ bf16 As[2 * AH];
  __shared__ bf16 Bs[2 * 4096];
  const int t = threadIdx.x;
  const int l = t & 63, w = t >> 6;
  const int lr = l >> 4, lc = l & 15;
  const int wm = (MT == 128) ? (w >> 1) : 0;
  const int wn = (MT == 128) ? (w & 1) : w;
  const int m0 = blockIdx.y * MT, n0 = blockIdx.x * 128;

  const int srow = t >> 2;                 // 0..63
  const int scol = (t & 3) * 8;
  const bf16* ga0 = A + (size_t)(m0 + srow) * K + scol;
  const bf16* ga1 = A + (size_t)(m0 + 64 + srow) * K + scol;   // MT==128 only
  const bf16* gb0 = Bt + (size_t)(n0 + srow) * ldb + scol;
  const bf16* gb1 = Bt + (size_t)(n0 + 64 + srow) * ldb + scol;

  f32x4 acc[4][NJ];
  for (int i = 0; i < 4; ++i)
    for (int j = 0; j < NJ; ++j) acc[i][j] = (f32x4){0.f, 0.f, 0.f, 0.f};

  for (int k0 = 0; k0 < K; k0 += 64) {
    async_copy16(ga0 + k0,      &As[w * 512]);
    async_copy16(ga0 + k0 + 32, &As[AH + w * 512]);
    if (MT == 128) {
      async_copy16(ga1 + k0,      &As[2048 + w * 512]);
      async_copy16(ga1 + k0 + 32, &As[AH + 2048 + w * 512]);
    }
    async_copy16(gb0 + k0,      &Bs[w * 512]);
    async_copy16(gb0 + k0 + 32, &Bs[4096 + w * 512]);
    async_copy16(gb1 + k0,      &Bs[2048 + w * 512]);
    async_copy16(gb1 + k0 + 32, &Bs[4096 + 2048 + w * 512]);
    __syncthreads();
    for (int h = 0; h < 2; ++h) {
      bf16x8 af[4], bfr[NJ];
      for (int i = 0; i < 4; ++i)
        af[i] = *(const bf16x8*)&As[h * AH + (wm * 64 + i * 16 + lc) * 32 + 8 * lr];
      for (int j = 0; j < NJ; ++j)
        bfr[j] = *(const bf16x8*)&Bs[h * 4096 + (wn * 16 * NJ + j * 16 + lc) * 32 + 8 * lr];
      for (int i = 0; i < 4; ++i)
        for (int j = 0; j < NJ; ++j)
          acc[i][j] = MFMA16(af[i], bfr[j], acc[i][j]);
    }
    __syncthreads();
  }

  const size_t Ns = (size_t)N;
  for (int i = 0; i < 4; ++i) {
    int rowb = m0 + wm * 64 + i * 16 + lr * 4;
    for (int j = 0; j < NJ; ++j) {
      int col = n0 + wn * 16 * NJ + j * 16 + lc;
      float bv = BIAS ? bias[col] : 0.f;
      for (int r = 0; r < 4; ++r) {
        int row = rowb + r;
        float vv = acc[i][j][r];
        if (BIAS) vv += bv;
        if (GELU) vv = 0.5f * vv * (1.f + erff(vv * 0.70710678118654752f));
        if (RES)  vv += res[(size_t)row * Ns + col];
        if (SPLIT) {
          // permuted layout: col = which*768 + h*64 + d  -> d consecutive with lc
          int which = col / 768;
          int rem = col - which * 768;
          int h = rem >> 6, d = rem & 63;
          int bb = row >> 11, tt = row & 2047;
          bf16* dst = which == 0 ? qo : (which == 1 ? ko : vo);
          dst[((size_t)((bb * 12 + h) * 2048 + tt)) * 64 + d] = (bf16)vv;
        } else if (OUTF32) {
          ((float*)Cv)[(size_t)row * Ns + col] = vv;
        } else {
          ((bf16*)Cv)[(size_t)row * Ns + col] = (bf16)vv;
        }
      }
    }
  }
}

// ---------- Flash attention v3 (proven R7): no online max, ones-frag rowsum ----------
__global__ __launch_bounds__(256) void attn_kernel(const bf16* __restrict__ q,
    const bf16* __restrict__ k, const bf16* __restrict__ v, bf16* __restrict__ out) {
  __shared__ bf16 Ks[64 * 72];
  __shared__ bf16 Vt[64 * 72];
  __shared__ bf16 Ps[4 * 32 * 72];
  const int t = threadIdx.x;
  const int l = t & 63, w = t >> 6;
  const int g = l >> 4, c = l & 15;
  const int bh = blockIdx.y;
  const int q0 = blockIdx.x * 128;
  const size_t base = (size_t)bh * (2048 * 64);
  const int qr = q0 + w * 32;
  bf16x8 aq[2][2];
  for (int rt = 0; rt < 2; ++rt) {
    aq[rt][0] = *(const bf16x8*)(q + base + (size_t)(qr + rt * 16 + c) * 64 + 8 * g);
    aq[rt][1] = *(const bf16x8*)(q + base + (size_t)(qr + rt * 16 + c) * 64 + 32 + 8 * g);
  }
  f32x4 O[2][4], O5[2];
  for (int rt = 0; rt < 2; ++rt) {
    for (int j = 0; j < 4; ++j) O[rt][j] = (f32x4){0.f, 0.f, 0.f, 0.f};
    O5[rt] = (f32x4){0.f, 0.f, 0.f, 0.f};
  }
  bf16x8 ones;
  for (int i = 0; i < 8; ++i) ones[i] = (bf16)1.0f;
  const int rr = t >> 3, so = t & 7;
  const float cs = 0.125f * 1.44269504089f;

  const bf16* kp = k + base + (size_t)(2 * rr) * 64 + so * 8;
  const bf16* vp = v + base + (size_t)(2 * rr) * 64 + so * 8;
  bf16x8 kr0 = *(const bf16x8*)kp;
  bf16x8 kr1 = *(const bf16x8*)(kp + 64);
  bf16x8 vr0 = *(const bf16x8*)vp;
  bf16x8 vr1 = *(const bf16x8*)(vp + 64);

  for (int j0 = 0; j0 < 2048; j0 += 64) {
    __syncthreads();
    *(bf16x8*)&Ks[(2 * rr) * 72 + so * 8] = kr0;
    *(bf16x8*)&Ks[(2 * rr + 1) * 72 + so * 8] = kr1;
    {
      int keyr = (2 * rr + 8 * so) & 63;
      for (int i = 0; i < 8; ++i) {
        int dd = so * 8 + i;
        union { bf16 h[2]; u32 u; } pu;
        pu.h[0] = vr0[i]; pu.h[1] = vr1[i];
        *(u32*)&Vt[dd * 72 + keyr] = pu.u;
      }
    }
    if (j0 + 64 < 2048) {
      kp += 64 * 64; vp += 64 * 64;
      kr0 = *(const bf16x8*)kp;
      kr1 = *(const bf16x8*)(kp + 64);
      vr0 = *(const bf16x8*)vp;
      vr1 = *(const bf16x8*)(vp + 64);
    }
    __syncthreads();
    f32x4 S[2][4];
    for (int m = 0; m < 4; ++m) {
      bf16x8 b0 = *(const bf16x8*)&Ks[(16 * m + c) * 72 + 8 * g];
      bf16x8 b1 = *(const bf16x8*)&Ks[(16 * m + c) * 72 + 32 + 8 * g];
      for (int rt = 0; rt < 2; ++rt) {
        f32x4 z = (f32x4){0.f, 0.f, 0.f, 0.f};
        z = MFMA16(aq[rt][0], b0, z);
        S[rt][m] = MFMA16(aq[rt][1], b1, z);
      }
    }
    for (int rt = 0; rt < 2; ++rt)
      for (int m = 0; m < 4; ++m)
        for (int r = 0; r < 4; ++r) {
          float p = exp2f(S[rt][m][r] * cs);
          Ps[w * 2304 + (rt * 16 + g * 4 + r) * 72 + 16 * m + c] = (bf16)p;
        }
    bf16x8 ap[2][2];
    for (int rt = 0; rt < 2; ++rt) {
      ap[rt][0] = *(const bf16x8*)&Ps[w * 2304 + (rt * 16 + c) * 72 + 8 * g];
      ap[rt][1] = *(const bf16x8*)&Ps[w * 2304 + (rt * 16 + c) * 72 + 32 + 8 * g];
    }
    for (int j = 0; j < 4; ++j) {
      int dd = j * 16 + c;
      int rot = 8 * (dd >> 3);
      bf16x8 bv0 = *(const bf16x8*)&Vt[dd * 72 + ((8 * g + rot) & 63)];
      bf16x8 bv1 = *(const bf16x8*)&Vt[dd * 72 + ((32 + 8 * g + rot) & 63)];
      for (int rt = 0; rt < 2; ++rt) {
        O[rt][j] = MFMA16(ap[rt][0], bv0, O[rt][j]);
        O[rt][j] = MFMA16(ap[rt][1], bv1, O[rt][j]);
      }
    }
    for (int rt = 0; rt < 2; ++rt) {
      O5[rt] = MFMA16(ap[rt][0], ones, O5[rt]);
      O5[rt] = MFMA16(ap[rt][1], ones, O5[rt]);
    }
  }
  const int b = bh / 12, h = bh % 12;
  for (int rt = 0; rt < 2; ++rt)
    for (int r = 0; r < 4; ++r) {
      float inv = 1.0f / O5[rt][r];
      int tok = q0 + w * 32 + rt * 16 + g * 4 + r;
      for (int j = 0; j < 4; ++j) {
        int col = h * 64 + j * 16 + c;
        out[(size_t)(b * 2048 + tok) * 768 + col] = (bf16)(O[rt][j][r] * inv);
      }
    }
}

// ---------- launch ----------
extern "C" void kernel_launch(void* const* d_in, const int* in_sizes, int n_in,
                              void* d_out, int out_size, void* d_ws, size_t ws_size,
                              hipStream_t stream) {
  static const long expected[9] = {6291456, 768, 768, 1769472, 589824, 2359296,
                                   3072, 2359296, 768};
  long f = 1; bool found = false;
  for (long ff = 1; ff <= 4 && !found; ff *= 2)
    for (int i = 0; i < n_in; ++i)
      if ((long)in_sizes[i] == 6291456L * ff) { f = ff; found = true; break; }
  int idx[9]; bool used[32] = {false};
  for (int s = 0; s < 9; ++s) {
    idx[s] = -1;
    if (found)
      for (int i = 0; i < n_in; ++i)
        if (!used[i] && (long)in_sizes[i] == expected[s] * f) { idx[s] = i; used[i] = true; break; }
    if (idx[s] < 0) idx[s] = s;
  }
  const float* x    = (const float*)d_in[idx[0]];
  const float* ln_g = (const float*)d_in[idx[1]];
  const float* ln_b = (const float*)d_in[idx[2]];
  const float* wqkv = (const float*)d_in[idx[3]];
  const float* wao  = (const float*)d_in[idx[4]];
  const float* wi   = (const float*)d_in[idx[5]];
  const float* bi   = (const float*)d_in[idx[6]];
  const float* wo   = (const float*)d_in[idx[7]];
  const float* bo   = (const float*)d_in[idx[8]];

  char* ws = (char*)d_ws;
  bf16*  norm = (bf16*)(ws);
  bf16*  wtq  = (bf16*)(ws + 12582912);
  bf16*  at   = (bf16*)(ws + 12582912);
  bf16*  hbuf = (bf16*)(ws + 12582912);
  bf16*  qb   = (bf16*)(ws + 25165824);
  bf16*  wta  = (bf16*)(ws + 25165824);
  bf16*  wti  = (bf16*)(ws + 26345472);
  bf16*  wto  = (bf16*)(ws + 31064064);
  bf16*  kb   = (bf16*)d_out;
  bf16*  vb   = (bf16*)((char*)d_out + 12582912);
  float* x1   = (float*)d_out;

  ln_kernel<<<8192, 256, 0, stream>>>(x, ln_g, ln_b, norm);
  castT_kernel<1><<<dim3(36, 12), 256, 0, stream>>>(wqkv, wtq, 768, 2304);
  gemm_bt<128,0,0,0,0,1><<<dim3(18, 64), 256, 0, stream>>>(
      norm, wtq, 768, nullptr, nullptr, nullptr, qb, kb, vb, 8192, 2304, 768);
  attn_kernel<<<dim3(16, 48), 256, 0, stream>>>(qb, kb, vb, at);
  castT_kernel<0><<<dim3(12, 12), 256, 0, stream>>>(wao, wta, 768, 768);
  castT_kernel<0><<<dim3(48, 12), 256, 0, stream>>>(wi,  wti, 768, 3072);
  castT_kernel<0><<<dim3(12, 48), 256, 0, stream>>>(wo,  wto, 3072, 768);
  // x1 = x + at @ w_attn_out  (fp32 into d_out; k/v dead)
  gemm_bt<64,1,0,0,1,0><<<dim3(6, 128), 256, 0, stream>>>(
      at, wta, 768, x1, nullptr, x, nullptr, nullptr, nullptr, 8192, 768, 768);
  // MLP: 4 x 768-wide slices; x1 accumulates in place
  for (int p = 0; p < 4; ++p) {
    gemm_bt<64,0,1,1,0,0><<<dim3(6, 128), 256, 0, stream>>>(
        norm, wti + (size_t)p * 768 * 768, 768, hbuf, bi + p * 768, nullptr,
        nullptr, nullptr, nullptr, 8192, 768, 768);
    if (p < 3)
      gemm_bt<64,1,0,0,1,0><<<dim3(6, 128), 256, 0, stream>>>(
          hbuf, wto + (size_t)p * 768, 3072, x1, nullptr, x1,
          nullptr, nullptr, nullptr, 8192, 768, 768);
    else
      gemm_bt<64,1,1,0,1,0><<<dim3(6, 128), 256, 0, stream>>>(
          hbuf, wto + (size_t)p * 768, 3072, x1, bo, x1,
          nullptr, nullptr, nullptr, 8192, 768, 768);
  }
}